// Round 1
// baseline (593.759 us; speedup 1.0000x reference)
//
#include <hip/hip_runtime.h>
#include <hip/hip_bf16.h>

// GetAffs: seg [1,1,4096,4096] f32 (integer labels), out [8,4096,4096] f32.
// out[o][i][j] = (zeroext(seg)[i+ox][j+oy] == seg[i][j]) ? 1.0f : 0.0f
// OFFSETS: (-1,0),(0,-1),(-2,0),(0,-2),(-4,0),(0,-4),(-8,0),(0,-8)
//
// R3: A/B the store path — NT streaming stores replaced with plain (L2-cached)
// float4 stores. Theory: 8 NT write streams at 2^26 stride share low address
// bits -> same-channel different-row DRAM thrash; cached stores let L2
// writeback batch full lines per channel (the 6.26 TB/s fill path).
// Row-band register-ring scheme unchanged from R2.

#define IMG_H 4096
#define IMG_W 4096
#define BAND  16

__device__ __forceinline__ float4 ld4(const float* p) { return *(const float4*)p; }

__device__ __forceinline__ void st4(float* p, float4 v) {
    *(float4*)p = v;
}

__device__ __forceinline__ float4 eq4(float4 a, float4 b) {
    return make_float4(a.x == b.x ? 1.0f : 0.0f,
                       a.y == b.y ? 1.0f : 0.0f,
                       a.z == b.z ? 1.0f : 0.0f,
                       a.w == b.w ? 1.0f : 0.0f);
}

__global__ __launch_bounds__(256) void GetAffs_83416854823610_kernel(
        const float* __restrict__ seg, float* __restrict__ out) {
    const int jq = blockIdx.x * 256 + threadIdx.x;  // float4 column group, 0..1023
    const int j  = jq << 2;                         // first of this thread's 4 cols
    const int i0 = blockIdx.y * BAND;               // first row of this band
    const float4 zero4 = make_float4(0.f, 0.f, 0.f, 0.f);

    // Ring: slot(row r) = (r - i0) & 7. Preload rows i0-8 .. i0-1 (zero if OOB).
    float4 hist[8];
#pragma unroll
    for (int k = 0; k < 8; ++k) {
        const int r = i0 - 8 + k;                   // slot = (r - i0) & 7 = k
        hist[k] = (r >= 0) ? ld4(seg + (size_t)r * IMG_W + j) : zero4;
    }

    const size_t HW = (size_t)IMG_H * IMG_W;

#pragma unroll
    for (int u = 0; u < BAND; ++u) {                // row i = i0 + u
        const int i = i0 + u;
        const float* row = seg + (size_t)i * IMG_W;
        const float4 c  = ld4(row + j);
        const float4 l1 = (j >= 4) ? ld4(row + j - 4) : zero4;  // cols j-4..j-1
        const float4 l2 = (j >= 8) ? ld4(row + j - 8) : zero4;  // cols j-8..j-5

        // vertical neighbors from the register ring (slots are compile-time)
        const float4 v1 = hist[(u + 7) & 7];        // row i-1
        const float4 v2 = hist[(u + 6) & 7];        // row i-2
        const float4 v4 = hist[(u + 4) & 7];        // row i-4
        const float4 v8 = hist[u & 7];              // row i-8

        // horizontal neighbors: element k of plane (0,-d) is seg[i][j+k-d]
        const float4 h1 = make_float4(l1.w, c.x, c.y, c.z);
        const float4 h2 = make_float4(l1.z, l1.w, c.x, c.y);
        const float4 h4 = l1;
        const float4 h8 = l2;

        const size_t base = (size_t)i * IMG_W + (size_t)j;
        st4(out + 0 * HW + base, eq4(v1, c));    // (-1, 0)
        st4(out + 1 * HW + base, eq4(h1, c));    // ( 0,-1)
        st4(out + 2 * HW + base, eq4(v2, c));    // (-2, 0)
        st4(out + 3 * HW + base, eq4(h2, c));    // ( 0,-2)
        st4(out + 4 * HW + base, eq4(v4, c));    // (-4, 0)
        st4(out + 5 * HW + base, eq4(h4, c));    // ( 0,-4)
        st4(out + 6 * HW + base, eq4(v8, c));    // (-8, 0)
        st4(out + 7 * HW + base, eq4(h8, c));    // ( 0,-8)

        hist[u & 7] = c;  // row i replaces row i-8 (already consumed as v8)
    }
}

extern "C" void kernel_launch(void* const* d_in, const int* in_sizes, int n_in,
                              void* d_out, int out_size, void* d_ws, size_t ws_size,
                              hipStream_t stream) {
    const float* seg = (const float*)d_in[0];
    float* out = (float*)d_out;
    // 1024 col-groups / 256 threads = 4 blocks in x; 4096/16 = 256 bands in y.
    dim3 grid((IMG_W / 4) / 256, IMG_H / BAND);
    dim3 block(256);
    GetAffs_83416854823610_kernel<<<grid, block, 0, stream>>>(seg, out);
}

// Round 2
// 567.359 us; speedup vs baseline: 1.0465x; 1.0465x over previous
//
#include <hip/hip_runtime.h>
#include <hip/hip_bf16.h>

// GetAffs: seg [1,1,4096,4096] f32 (integer labels), out [8,4096,4096] f32.
// out[o][i][j] = (zeroext(seg)[i+ox][j+oy] == seg[i][j]) ? 1.0f : 0.0f
// OFFSETS: (-1,0),(0,-1),(-2,0),(0,-2),(-4,0),(0,-4),(-8,0),(0,-8)
//
// R4: store-contiguity restructure. Theory: the 8 output planes are 2^26 B
// apart -> per-wave plane-interleaved stores hit ONE channel with 8 different
// DRAM pages each iteration (page thrash; kernel ran at ~2.75 TB/s vs the
// 6.25 TB/s the harness fill proves). New shape: block = 1024 threads = full
// 4096-col row, BAND=8. Stage 16 rows (8 halo + 8 band) in registers;
// horizontal planes stored during staging (16 KB contiguous per row per
// plane per block, l1/l2 loads L1-hot); vertical planes plane-OUTER from
// registers (128 KB contiguous per (block,plane)). NT stores kept (R3 showed
// cached stores regress). All reg indices compile-time (full unroll).

#define IMG_H 4096
#define IMG_W 4096
#define BAND  8

typedef float floatx4 __attribute__((ext_vector_type(4)));

__device__ __forceinline__ float4 ld4(const float* p) { return *(const float4*)p; }

__device__ __forceinline__ void st4_nt(float* p, float4 v) {
    floatx4 x = { v.x, v.y, v.z, v.w };
    __builtin_nontemporal_store(x, (floatx4*)p);
}

__device__ __forceinline__ float4 eq4(float4 a, float4 b) {
    return make_float4(a.x == b.x ? 1.0f : 0.0f,
                       a.y == b.y ? 1.0f : 0.0f,
                       a.z == b.z ? 1.0f : 0.0f,
                       a.w == b.w ? 1.0f : 0.0f);
}

__global__ __launch_bounds__(1024, 4) void GetAffs_83416854823610_kernel(
        const float* __restrict__ seg, float* __restrict__ out) {
    const int j  = threadIdx.x << 2;          // this thread's 4 columns (full row per block)
    const int i0 = blockIdx.x * BAND;         // first band row
    const float4 zero4 = make_float4(0.f, 0.f, 0.f, 0.f);
    const size_t HW = (size_t)IMG_H * IMG_W;

    // c[k] = seg row (i0 - 8 + k), k=0..15: 8 halo rows + 8 band rows.
    float4 c[16];

    // ---- Phase 1: stage rows; compute+store horizontal planes for band rows.
#pragma unroll
    for (int k = 0; k < 16; ++k) {
        const int r = i0 - 8 + k;
        c[k] = (r >= 0) ? ld4(seg + (size_t)r * IMG_W + j) : zero4;
        if (k >= 8) {                          // band row i = r
            const float* row = seg + (size_t)r * IMG_W;
            const float4 cc = c[k];
            const float4 l1 = (j >= 4) ? ld4(row + j - 4) : zero4;  // cols j-4..j-1
            const float4 l2 = (j >= 8) ? ld4(row + j - 8) : zero4;  // cols j-8..j-5
            const float4 h1 = make_float4(l1.w, cc.x, cc.y, cc.z);  // cols j-1..j+2
            const float4 h2 = make_float4(l1.z, l1.w, cc.x, cc.y);  // cols j-2..j+1
            const size_t base = (size_t)r * IMG_W + (size_t)j;
            st4_nt(out + 1 * HW + base, eq4(h1, cc));   // ( 0,-1)
            st4_nt(out + 3 * HW + base, eq4(h2, cc));   // ( 0,-2)
            st4_nt(out + 5 * HW + base, eq4(l1, cc));   // ( 0,-4)
            st4_nt(out + 7 * HW + base, eq4(l2, cc));   // ( 0,-8)
        }
    }

    // ---- Phase 2: vertical planes, plane-outer, pure register -> store.
    // out[p][i0+u][j] = (c[8+u-d] == c[8+u]); indices compile-time via unroll.
#define VPLANE(P, D)                                                        \
    _Pragma("unroll")                                                       \
    for (int u = 0; u < BAND; ++u) {                                        \
        const size_t base = (size_t)(i0 + u) * IMG_W + (size_t)j;           \
        st4_nt(out + (P) * HW + base, eq4(c[8 + u - (D)], c[8 + u]));       \
    }

    VPLANE(0, 1)   // (-1, 0)
    VPLANE(2, 2)   // (-2, 0)
    VPLANE(4, 4)   // (-4, 0)
    VPLANE(6, 8)   // (-8, 0)
#undef VPLANE
}

extern "C" void kernel_launch(void* const* d_in, const int* in_sizes, int n_in,
                              void* d_out, int out_size, void* d_ws, size_t ws_size,
                              hipStream_t stream) {
    const float* seg = (const float*)d_in[0];
    float* out = (float*)d_out;
    dim3 grid(IMG_H / BAND);   // 512 blocks, each = 8 rows x full width
    dim3 block(1024);
    GetAffs_83416854823610_kernel<<<grid, block, 0, stream>>>(seg, out);
}